// Round 18
// baseline (666.966 us; speedup 1.0000x reference)
//
#include <hip/hip_runtime.h>

// BiLSTM: B=2048, T=200, D=U=128, 2 layers, bidirectional, merge='ave'.
// R17 = R16/R12 (610us keeper) + fused sigmoid*tanh in cells:
//   sigm(a)*tanh(b) = (B-1)/[(1+A)(B+1)], A=e^-a, B=e^2b  -> 1 rcp not 2.
// Cuts trans-pipe ops 80->64 per thread-step (v_rcp 40->24); exp terms
// unchanged (same error profile). c clamped to +/-15 before e^{2c} to
// avoid inf*0 NaN (tanh saturated there anyway). All else R16 verbatim:
// dual accs, interleaved per-ks MFMA, trailing cells, 1 barrier/step,
// W0,U0,W1 in regs (192), U1 in LDS (128KB), c-state f16 LDS, biases in
// d_ws. LDS 160KB. FETCH~200MB = no-spill guard.

#define NB   2048
#define NTT  200
#define ND   128
#define NTHR 512   // 8 waves

typedef _Float16 f16x8 __attribute__((ext_vector_type(8)));
typedef _Float16 f16x4 __attribute__((ext_vector_type(4)));
typedef float    f32x4 __attribute__((ext_vector_type(4)));

#define BARRIER() asm volatile("s_waitcnt lgkmcnt(0)\n\ts_barrier" ::: "memory")
#define MFMA16(A,B,C) __builtin_amdgcn_mfma_f32_16x16x32_f16((A),(B),(C),0,0,0)

__device__ __forceinline__ float rcp_f(float x){ return __builtin_amdgcn_rcpf(x); }
__device__ __forceinline__ float sigm(float x){ return rcp_f(1.f + __expf(-x)); }
// fused sigm(a)*tanh(b): one rcp. A=e^-a, B=e^2b -> (B-1)/((1+A)(B+1))
__device__ __forceinline__ float sigm_tanh(float a, float b){
  float A = __expf(-a);
  float B = __expf(2.f*b);
  float t = B + 1.f;
  return (B - 1.f) * rcp_f(__builtin_fmaf(A, t, t));
}

// ---- weight repack to fp16 frags: pk[dir][m][CT][ks][lane][8], m={W0,U0,W1,U1}
__global__ void __launch_bounds__(256)
repack_w(const float* __restrict__ Wf, const float* __restrict__ Uf,
         const float* __restrict__ Wb, const float* __restrict__ Ub,
         _Float16* __restrict__ pk)
{
  int flat = blockIdx.x*256 + threadIdx.x;        // 0 .. 524287
  int j  = flat & 7;
  int lx = (flat >> 3)  & 63;
  int ks = (flat >> 9)  & 3;
  int CT = (flat >> 11) & 31;
  int m  = (flat >> 16) & 3;
  int dr = (flat >> 18) & 1;
  int k  = ks*32 + (lx >> 4)*8 + j;
  int cc = CT*16 + (lx & 15);
  const float* src = dr ? ((m & 1) ? Ub : Wb) : ((m & 1) ? Uf : Wf);
  int layer = m >> 1;
  pk[flat] = (_Float16)src[((size_t)layer*ND + k)*512 + cc];
}

// ---- bias repack: bp[dir][w][l][layer][i] f32 at pk byte offset 1MB.
__global__ void __launch_bounds__(512)
repack_b(const float* __restrict__ bf_, const float* __restrict__ bb_,
         float* __restrict__ bp)
{
  for (int k = 0; k < 16; ++k){
    int flat = threadIdx.x + k*512;     // 0..8191
    int i     = flat & 3;
    int layer = (flat >> 2) & 1;
    int l     = (flat >> 3) & 63;
    int w     = (flat >> 9) & 7;
    int dr    = (flat >> 12) & 1;
    const float* B = dr ? bb_ : bf_;
    bp[flat] = B[layer*512 + 16*w + (l & 15) + 128*i];
  }
}

__global__ void __launch_bounds__(NTHR, 2)
bilstm_mfma(const float* __restrict__ x,
            const _Float16* __restrict__ pk,
            float* __restrict__ out)
{
  extern __shared__ char smem_raw[];
  _Float16* u1s = (_Float16*)smem_raw;   // 65536 halves (128KB)
  _Float16* h0a = u1s + 65536;           // 2 x 2048 (8KB)
  _Float16* h1a = h0a + 4096;            // 2 x 2048 (8KB)
  _Float16* xb  = h1a + 4096;            // 2 x 2048 (8KB)
  _Float16* cls = xb  + 4096;            // c0: [512][4], c1: +2048 (8KB) = 160KB

  const int tid = threadIdx.x;
  const int dir = blockIdx.y;
  const int b0  = blockIdx.x * 16;
  const int w    = tid >> 6;         // wave 0..7
  const int l    = tid & 63;
  const int kg   = l >> 4;           // 0..3
  const int unit = 16*w + (l & 15);

  const f16x8* PKH = (const f16x8*)pk;
  const float* bp  = (const float*)(pk + 524288) + (size_t)((dir*8 + w)*64 + l)*8;

  // ---- stage U1 into LDS (once)
  {
    const f16x8* u1g = PKH + (size_t)(dir*4 + 3)*32*4*64;
    f16x8* u1w = (f16x8*)u1s;
    for (int idx = tid; idx < 8192; idx += NTHR) u1w[idx] = u1g[idx];
  }

  // ---- resident W0,U0,W1 fragments (192 regs/lane)
  f16x8 w0r[4][4], u0r[4][4], w1r[4][4];   // [i][ks]
  #pragma unroll
  for (int i = 0; i < 4; ++i)
    #pragma unroll
    for (int ks = 0; ks < 4; ++ks){
      w0r[i][ks] = PKH[(size_t)(((dir*4 + 0)*32 + (w + 8*i))*4 + ks)*64 + l];
      u0r[i][ks] = PKH[(size_t)(((dir*4 + 1)*32 + (w + 8*i))*4 + ks)*64 + l];
      w1r[i][ks] = PKH[(size_t)(((dir*4 + 2)*32 + (w + 8*i))*4 + ks)*64 + l];
    }
  const f16x8* u1d = (const f16x8*)u1s;

  // zero initial h and c state
  for (int i = tid; i < 4096; i += NTHR){
    h0a[i] = (_Float16)0.f; h1a[i] = (_Float16)0.f; cls[i] = (_Float16)0.f;
  }

  const int er = tid >> 5;           // 0..15
  const int ej = (tid & 31) * 4;     // 0..124
  const int xidx  = ((ej >> 3) << 7) + (er << 3) + (ej & 7);
  const int hbase = ((unit >> 3) << 7) + (unit & 7);
  const int dstepN = dir ? -ND : ND;

  unsigned xoff  = (unsigned)(((b0 + er)*NTT + (dir ? NTT-2 : 1))*ND + ej);
  const unsigned obase = (unsigned)((b0 + kg*4)*NTT*ND + unit);
  int teN = (dir ? (NTT-1) : 0) * ND;
  _Float16* cl0 = cls + tid*4;       // c1 at imm offset +2048 halves (4096B)

  // prologue: stage x(0) into xb buf0
  {
    float4 xv = *(const float4*)(x + (xoff - dstepN));
    f16x4 hx;
    hx[0]=(_Float16)xv.x; hx[1]=(_Float16)xv.y; hx[2]=(_Float16)xv.z; hx[3]=(_Float16)xv.w;
    *(f16x4*)(xb + xidx) = hx;
  }

  __syncthreads();

  #pragma clang loop unroll(disable)
  for (int t = 0; t < NTT; ++t){
    const int rbo = (t & 1) << 11;     // read-buffer half offset (halves)
    const int wbo = rbo ^ 2048;

    // issue x(t+1) load first (oldest vm op)
    float4 xv = *(const float4*)(x + xoff);
    if (t + 2 < NTT) xoff += dstepN;

    // ---------- fused dual-acc MFMA block: L1(t-1) and L0(t)
    f32x4 a1[4], a0[4];
    #pragma unroll
    for (int i = 0; i < 4; ++i){ a1[i] = (f32x4){0,0,0,0}; a0[i] = (f32x4){0,0,0,0}; }
    #pragma unroll
    for (int ks = 0; ks < 4; ++ks){
      f16x8 ah0 = *(const f16x8*)(h0a + rbo + ks*512 + l*8);
      f16x8 ah1 = *(const f16x8*)(h1a + rbo + ks*512 + l*8);
      #pragma unroll
      for (int i = 0; i < 4; ++i){
        f16x8 u1f = u1d[((w + 8*i)*4 + ks)*64 + l];
        a1[i] = MFMA16(ah0, w1r[i][ks], a1[i]);
        a1[i] = MFMA16(ah1, u1f,        a1[i]);
      }
      f16x8 axf = *(const f16x8*)(xb + rbo + ks*512 + l*8);
      #pragma unroll
      for (int i = 0; i < 4; ++i){
        a0[i] = MFMA16(axf, w0r[i][ks], a0[i]);
        a0[i] = MFMA16(ah0, u0r[i][ks], a0[i]);
      }
    }

    // bias loads (L1$-hot; older than this step's atomics)
    float4 b0v = *(const float4*)(bp);
    float4 b1v = *(const float4*)(bp + 4);

    // ---------- cell1 (depends only on a1)
    if (t > 0){
      const int teoN = teN - dstepN;
      f16x4 c1h = *(const f16x4*)(cl0 + 2048);
      f16x4 c1n;
      #pragma unroll
      for (int q = 0; q < 4; ++q){
        float fg  = sigm(a1[1][q] + b1v.y);
        float igg = sigm_tanh(a1[0][q] + b1v.x, a1[2][q] + b1v.z);
        float cv  = __builtin_fmaf(fg, (float)c1h[q], igg);
        c1n[q] = (_Float16)cv;
        float cc = fminf(fmaxf(cv, -15.f), 15.f);
        float hh = sigm_tanh(a1[3][q] + b1v.w, cc);
        h1a[wbo + hbase + (kg*4 + q)*8] = (_Float16)hh;
        atomicAdd(out + (obase + (unsigned)(q*NTT*ND) + (unsigned)teoN), 0.5f*hh);
      }
      *(f16x4*)(cl0 + 2048) = c1n;
    }
    // t==0: h1a[wbo] stays zero (= h1(-1)); c1 LDS stays 0.

    // ---------- cell0
    {
      f16x4 c0h = *(const f16x4*)(cl0);
      f16x4 c0n;
      #pragma unroll
      for (int q = 0; q < 4; ++q){
        float fg  = sigm(a0[1][q] + b0v.y);
        float igg = sigm_tanh(a0[0][q] + b0v.x, a0[2][q] + b0v.z);
        float cv  = __builtin_fmaf(fg, (float)c0h[q], igg);
        c0n[q] = (_Float16)cv;
        float cc = fminf(fmaxf(cv, -15.f), 15.f);
        float hh = sigm_tanh(a0[3][q] + b0v.w, cc);
        h0a[wbo + hbase + (kg*4 + q)*8] = (_Float16)hh;
      }
      *(f16x4*)(cl0) = c0n;
    }

    // stage x(t+1) into xb[wbo]
    {
      f16x4 hx;
      hx[0]=(_Float16)xv.x; hx[1]=(_Float16)xv.y; hx[2]=(_Float16)xv.z; hx[3]=(_Float16)xv.w;
      *(f16x4*)(xb + wbo + xidx) = hx;
    }

    BARRIER();   // h0(t), h1(t-1), x(t+1) ready for iter t+1
    teN += dstepN;
  }

  // ---- epilogue: L1(NTT-1). h0(199), h1(198) in buffers rb = NTT&1 = 0.
  {
    f32x4 a1[4];
    #pragma unroll
    for (int i = 0; i < 4; ++i) a1[i] = (f32x4){0,0,0,0};
    #pragma unroll
    for (int ks = 0; ks < 4; ++ks){
      f16x8 ah0 = *(const f16x8*)(h0a + ks*512 + l*8);
      f16x8 ah1 = *(const f16x8*)(h1a + ks*512 + l*8);
      #pragma unroll
      for (int i = 0; i < 4; ++i){
        f16x8 u1f = u1d[((w + 8*i)*4 + ks)*64 + l];
        a1[i] = MFMA16(ah0, w1r[i][ks], a1[i]);
        a1[i] = MFMA16(ah1, u1f,        a1[i]);
      }
    }
    float4 b1v = *(const float4*)(bp + 4);
    f16x4 c1h = *(const f16x4*)(cl0 + 2048);
    const int teoN = teN - dstepN;     // = te(199)*ND
    #pragma unroll
    for (int q = 0; q < 4; ++q){
      float fg  = sigm(a1[1][q] + b1v.y);
      float igg = sigm_tanh(a1[0][q] + b1v.x, a1[2][q] + b1v.z);
      float cv  = __builtin_fmaf(fg, (float)c1h[q], igg);
      float cc  = fminf(fmaxf(cv, -15.f), 15.f);
      float hh  = sigm_tanh(a1[3][q] + b1v.w, cc);
      atomicAdd(out + (obase + (unsigned)(q*NTT*ND) + (unsigned)teoN), 0.5f*hh);
    }
  }
}

extern "C" void kernel_launch(void* const* d_in, const int* in_sizes, int n_in,
                              void* d_out, int out_size, void* d_ws, size_t ws_size,
                              hipStream_t stream)
{
  const float* x  = (const float*)d_in[0];
  const float* Wf = (const float*)d_in[1];
  const float* Uf = (const float*)d_in[2];
  const float* bf = (const float*)d_in[3];
  const float* Wb = (const float*)d_in[4];
  const float* Ub = (const float*)d_in[5];
  const float* bb = (const float*)d_in[6];
  float* out = (float*)d_out;

  _Float16* pk = (_Float16*)d_ws;          // 1MB packed fp16 weights + 32KB bias
  float* bp = (float*)(pk + 524288);

  (void)hipFuncSetAttribute((const void*)bilstm_mfma,
                            hipFuncAttributeMaxDynamicSharedMemorySize, 163840);

  repack_w<<<2048, 256, 0, stream>>>(Wf, Uf, Wb, Ub, pk);
  repack_b<<<1, 512, 0, stream>>>(bf, bb, bp);
  hipMemsetAsync(out, 0, (size_t)out_size*sizeof(float), stream);
  dim3 grid(NB/16, 2), blk(NTHR);
  bilstm_mfma<<<grid, blk, 163840, stream>>>(x, pk, out);
}

// Round 19
// 600.740 us; speedup vs baseline: 1.1102x; 1.1102x over previous
//
#include <hip/hip_runtime.h>

// BiLSTM: B=2048, T=200, D=U=128, 2 layers, bidirectional, merge='ave'.
// R18 = R12/R16 (610us keeper) + HOISTED per-step loads: the 2 bias
// dwordx4 (L1-hot, ~150cy) and 2 c-state ds_read_b64 (~120cy) move from
// just-before-cell1 (exposed on the critical path) to the step top,
// under ~2600cy of MFMA-block cover. Compiler can't hoist the c-reads
// itself (can't prove no-alias vs h-writes in dynamic LDS). Chains
// untouched (R13/R15/R17 all showed chain edits regress). All else
// R16-verbatim: dual accs, interleaved per-ks MFMA, trailing cells,
// 1 barrier/step, W0/U0/W1 in regs (192), U1 LDS 128KB, c f16 LDS,
// biases in d_ws. LDS 160KB. FETCH~200MB = no-spill guard.

#define NB   2048
#define NTT  200
#define ND   128
#define NTHR 512   // 8 waves

typedef _Float16 f16x8 __attribute__((ext_vector_type(8)));
typedef _Float16 f16x4 __attribute__((ext_vector_type(4)));
typedef float    f32x4 __attribute__((ext_vector_type(4)));

#define BARRIER() asm volatile("s_waitcnt lgkmcnt(0)\n\ts_barrier" ::: "memory")
#define MFMA16(A,B,C) __builtin_amdgcn_mfma_f32_16x16x32_f16((A),(B),(C),0,0,0)

__device__ __forceinline__ float rcp_f(float x){ return __builtin_amdgcn_rcpf(x); }
__device__ __forceinline__ float sigm(float x){ return rcp_f(1.f + __expf(-x)); }
__device__ __forceinline__ float tanh_f(float x){ return 1.f - 2.f*rcp_f(__expf(2.f*x) + 1.f); }

// ---- weight repack to fp16 frags: pk[dir][m][CT][ks][lane][8], m={W0,U0,W1,U1}
__global__ void __launch_bounds__(256)
repack_w(const float* __restrict__ Wf, const float* __restrict__ Uf,
         const float* __restrict__ Wb, const float* __restrict__ Ub,
         _Float16* __restrict__ pk)
{
  int flat = blockIdx.x*256 + threadIdx.x;        // 0 .. 524287
  int j  = flat & 7;
  int lx = (flat >> 3)  & 63;
  int ks = (flat >> 9)  & 3;
  int CT = (flat >> 11) & 31;
  int m  = (flat >> 16) & 3;
  int dr = (flat >> 18) & 1;
  int k  = ks*32 + (lx >> 4)*8 + j;
  int cc = CT*16 + (lx & 15);
  const float* src = dr ? ((m & 1) ? Ub : Wb) : ((m & 1) ? Uf : Wf);
  int layer = m >> 1;
  pk[flat] = (_Float16)src[((size_t)layer*ND + k)*512 + cc];
}

// ---- bias repack: bp[dir][w][l][layer][i] f32 at pk byte offset 1MB.
__global__ void __launch_bounds__(512)
repack_b(const float* __restrict__ bf_, const float* __restrict__ bb_,
         float* __restrict__ bp)
{
  for (int k = 0; k < 16; ++k){
    int flat = threadIdx.x + k*512;     // 0..8191
    int i     = flat & 3;
    int layer = (flat >> 2) & 1;
    int l     = (flat >> 3) & 63;
    int w     = (flat >> 9) & 7;
    int dr    = (flat >> 12) & 1;
    const float* B = dr ? bb_ : bf_;
    bp[flat] = B[layer*512 + 16*w + (l & 15) + 128*i];
  }
}

__global__ void __launch_bounds__(NTHR, 2)
bilstm_mfma(const float* __restrict__ x,
            const _Float16* __restrict__ pk,
            float* __restrict__ out)
{
  extern __shared__ char smem_raw[];
  _Float16* u1s = (_Float16*)smem_raw;   // 65536 halves (128KB)
  _Float16* h0a = u1s + 65536;           // 2 x 2048 (8KB)
  _Float16* h1a = h0a + 4096;            // 2 x 2048 (8KB)
  _Float16* xb  = h1a + 4096;            // 2 x 2048 (8KB)
  _Float16* cls = xb  + 4096;            // c0: [512][4], c1: +2048 (8KB) = 160KB

  const int tid = threadIdx.x;
  const int dir = blockIdx.y;
  const int b0  = blockIdx.x * 16;
  const int w    = tid >> 6;         // wave 0..7
  const int l    = tid & 63;
  const int kg   = l >> 4;           // 0..3
  const int unit = 16*w + (l & 15);

  const f16x8* PKH = (const f16x8*)pk;
  const float* bp  = (const float*)(pk + 524288) + (size_t)((dir*8 + w)*64 + l)*8;

  // ---- stage U1 into LDS (once)
  {
    const f16x8* u1g = PKH + (size_t)(dir*4 + 3)*32*4*64;
    f16x8* u1w = (f16x8*)u1s;
    for (int idx = tid; idx < 8192; idx += NTHR) u1w[idx] = u1g[idx];
  }

  // ---- resident W0,U0,W1 fragments (192 regs/lane)
  f16x8 w0r[4][4], u0r[4][4], w1r[4][4];   // [i][ks]
  #pragma unroll
  for (int i = 0; i < 4; ++i)
    #pragma unroll
    for (int ks = 0; ks < 4; ++ks){
      w0r[i][ks] = PKH[(size_t)(((dir*4 + 0)*32 + (w + 8*i))*4 + ks)*64 + l];
      u0r[i][ks] = PKH[(size_t)(((dir*4 + 1)*32 + (w + 8*i))*4 + ks)*64 + l];
      w1r[i][ks] = PKH[(size_t)(((dir*4 + 2)*32 + (w + 8*i))*4 + ks)*64 + l];
    }
  const f16x8* u1d = (const f16x8*)u1s;

  // zero initial h and c state
  for (int i = tid; i < 4096; i += NTHR){
    h0a[i] = (_Float16)0.f; h1a[i] = (_Float16)0.f; cls[i] = (_Float16)0.f;
  }

  const int er = tid >> 5;           // 0..15
  const int ej = (tid & 31) * 4;     // 0..124
  const int xidx  = ((ej >> 3) << 7) + (er << 3) + (ej & 7);
  const int hbase = ((unit >> 3) << 7) + (unit & 7);
  const int dstepN = dir ? -ND : ND;

  unsigned xoff  = (unsigned)(((b0 + er)*NTT + (dir ? NTT-2 : 1))*ND + ej);
  const unsigned obase = (unsigned)((b0 + kg*4)*NTT*ND + unit);
  int teN = (dir ? (NTT-1) : 0) * ND;
  _Float16* cl0 = cls + tid*4;       // c1 at imm offset +2048 halves (4096B)

  // prologue: stage x(0) into xb buf0
  {
    float4 xv = *(const float4*)(x + (xoff - dstepN));
    f16x4 hx;
    hx[0]=(_Float16)xv.x; hx[1]=(_Float16)xv.y; hx[2]=(_Float16)xv.z; hx[3]=(_Float16)xv.w;
    *(f16x4*)(xb + xidx) = hx;
  }

  __syncthreads();

  #pragma clang loop unroll(disable)
  for (int t = 0; t < NTT; ++t){
    const int rbo = (t & 1) << 11;     // read-buffer half offset (halves)
    const int wbo = rbo ^ 2048;

    // issue x(t+1) load first (oldest vm op)
    float4 xv = *(const float4*)(x + xoff);
    if (t + 2 < NTT) xoff += dstepN;

    // HOISTED: bias loads (L1-hot) + private c-state ds_reads issue here,
    // covered by the ~2600cy MFMA block below. Safe: c written before the
    // previous barrier (lgkm-drained); bias/c untouched by other threads.
    float4 b0v = *(const float4*)(bp);
    float4 b1v = *(const float4*)(bp + 4);
    f16x4 c1h = *(const f16x4*)(cl0 + 2048);
    f16x4 c0h = *(const f16x4*)(cl0);

    // ---------- fused dual-acc MFMA block: L1(t-1) and L0(t)
    f32x4 a1[4], a0[4];
    #pragma unroll
    for (int i = 0; i < 4; ++i){ a1[i] = (f32x4){0,0,0,0}; a0[i] = (f32x4){0,0,0,0}; }
    #pragma unroll
    for (int ks = 0; ks < 4; ++ks){
      f16x8 ah0 = *(const f16x8*)(h0a + rbo + ks*512 + l*8);
      f16x8 ah1 = *(const f16x8*)(h1a + rbo + ks*512 + l*8);
      #pragma unroll
      for (int i = 0; i < 4; ++i){
        f16x8 u1f = u1d[((w + 8*i)*4 + ks)*64 + l];
        a1[i] = MFMA16(ah0, w1r[i][ks], a1[i]);
        a1[i] = MFMA16(ah1, u1f,        a1[i]);
      }
      f16x8 axf = *(const f16x8*)(xb + rbo + ks*512 + l*8);
      #pragma unroll
      for (int i = 0; i < 4; ++i){
        a0[i] = MFMA16(axf, w0r[i][ks], a0[i]);
        a0[i] = MFMA16(ah0, u0r[i][ks], a0[i]);
      }
    }

    // ---------- cell1 (depends only on a1; b1v/c1h already resident)
    if (t > 0){
      const int teoN = teN - dstepN;
      f16x4 c1n;
      #pragma unroll
      for (int q = 0; q < 4; ++q){
        float ig = sigm(a1[0][q] + b1v.x);
        float fg = sigm(a1[1][q] + b1v.y);
        float gg = tanh_f(a1[2][q] + b1v.z);
        float og = sigm(a1[3][q] + b1v.w);
        float cv = __builtin_fmaf(fg, (float)c1h[q], ig*gg);
        c1n[q] = (_Float16)cv;
        float hh = og * tanh_f(cv);
        h1a[wbo + hbase + (kg*4 + q)*8] = (_Float16)hh;
        atomicAdd(out + (obase + (unsigned)(q*NTT*ND) + (unsigned)teoN), 0.5f*hh);
      }
      *(f16x4*)(cl0 + 2048) = c1n;
    }
    // t==0: h1a[wbo] stays zero (= h1(-1)); c1 LDS stays 0.

    // ---------- cell0
    {
      f16x4 c0n;
      #pragma unroll
      for (int q = 0; q < 4; ++q){
        float ig = sigm(a0[0][q] + b0v.x);
        float fg = sigm(a0[1][q] + b0v.y);
        float gg = tanh_f(a0[2][q] + b0v.z);
        float og = sigm(a0[3][q] + b0v.w);
        float cv = __builtin_fmaf(fg, (float)c0h[q], ig*gg);
        c0n[q] = (_Float16)cv;
        float hh = og * tanh_f(cv);
        h0a[wbo + hbase + (kg*4 + q)*8] = (_Float16)hh;
      }
      *(f16x4*)(cl0) = c0n;
    }

    // stage x(t+1) into xb[wbo]
    {
      f16x4 hx;
      hx[0]=(_Float16)xv.x; hx[1]=(_Float16)xv.y; hx[2]=(_Float16)xv.z; hx[3]=(_Float16)xv.w;
      *(f16x4*)(xb + wbo + xidx) = hx;
    }

    BARRIER();   // h0(t), h1(t-1), x(t+1) ready for iter t+1
    teN += dstepN;
  }

  // ---- epilogue: L1(NTT-1). h0(199), h1(198) in buffers rb = NTT&1 = 0.
  {
    f32x4 a1[4];
    #pragma unroll
    for (int i = 0; i < 4; ++i) a1[i] = (f32x4){0,0,0,0};
    #pragma unroll
    for (int ks = 0; ks < 4; ++ks){
      f16x8 ah0 = *(const f16x8*)(h0a + ks*512 + l*8);
      f16x8 ah1 = *(const f16x8*)(h1a + ks*512 + l*8);
      #pragma unroll
      for (int i = 0; i < 4; ++i){
        f16x8 u1f = u1d[((w + 8*i)*4 + ks)*64 + l];
        a1[i] = MFMA16(ah0, w1r[i][ks], a1[i]);
        a1[i] = MFMA16(ah1, u1f,        a1[i]);
      }
    }
    float4 b1v = *(const float4*)(bp + 4);
    f16x4 c1h = *(const f16x4*)(cl0 + 2048);
    const int teoN = teN - dstepN;     // = te(199)*ND
    #pragma unroll
    for (int q = 0; q < 4; ++q){
      float ig = sigm(a1[0][q] + b1v.x);
      float fg = sigm(a1[1][q] + b1v.y);
      float gg = tanh_f(a1[2][q] + b1v.z);
      float og = sigm(a1[3][q] + b1v.w);
      float cv = __builtin_fmaf(fg, (float)c1h[q], ig*gg);
      float hh = og * tanh_f(cv);
      atomicAdd(out + (obase + (unsigned)(q*NTT*ND) + (unsigned)teoN), 0.5f*hh);
    }
  }
}

extern "C" void kernel_launch(void* const* d_in, const int* in_sizes, int n_in,
                              void* d_out, int out_size, void* d_ws, size_t ws_size,
                              hipStream_t stream)
{
  const float* x  = (const float*)d_in[0];
  const float* Wf = (const float*)d_in[1];
  const float* Uf = (const float*)d_in[2];
  const float* bf = (const float*)d_in[3];
  const float* Wb = (const float*)d_in[4];
  const float* Ub = (const float*)d_in[5];
  const float* bb = (const float*)d_in[6];
  float* out = (float*)d_out;

  _Float16* pk = (_Float16*)d_ws;          // 1MB packed fp16 weights + 32KB bias
  float* bp = (float*)(pk + 524288);

  (void)hipFuncSetAttribute((const void*)bilstm_mfma,
                            hipFuncAttributeMaxDynamicSharedMemorySize, 163840);

  repack_w<<<2048, 256, 0, stream>>>(Wf, Uf, Wb, Ub, pk);
  repack_b<<<1, 512, 0, stream>>>(bf, bb, bp);
  hipMemsetAsync(out, 0, (size_t)out_size*sizeof(float), stream);
  dim3 grid(NB/16, 2), blk(NTHR);
  bilstm_mfma<<<grid, blk, 163840, stream>>>(x, pk, out);
}